// Round 6
// baseline (759.801 us; speedup 1.0000x reference)
//
#include <hip/hip_runtime.h>

#define NN 1024
#define NT 512
#define NW 32
#define INF_KEY 0x7FFFFFFFu

typedef unsigned int u32;
typedef unsigned long long u64;

// ---- A0: root hard bits ----
__global__ __launch_bounds__(1024) void root_bits_kernel(
    const float* __restrict__ rp, const float* __restrict__ gr, u32* __restrict__ rootbits)
{
    int tid = threadIdx.x;
    float p = rp[tid];
    float2 g = reinterpret_cast<const float2*>(gr)[tid];
    bool root = (p + g.x) > ((1.0f - p) + g.y);
    u64 m = __ballot(root);
    if ((tid & 31) == 0) rootbits[tid >> 5] = (u32)(m >> (tid & 32));
}

// ---- A1: edge hard bits + root dag rows written directly ----
__global__ void edge_bits_kernel(const float* __restrict__ ep, const float* __restrict__ ge,
                                 const u32* __restrict__ rootbits,
                                 u32* __restrict__ E, u32* __restrict__ dagbits)
{
    int idx = blockIdx.x * blockDim.x + threadIdx.x;
    int i = idx >> 10;
    float p = ep[idx];
    float2 g = reinterpret_cast<const float2*>(ge)[idx];
    bool hard = (p + g.x) > ((1.0f - p) + g.y);
    u64 m = __ballot(hard);
    int lane = threadIdx.x & 63;
    if ((lane & 31) == 0) {
        int w = idx >> 5;
        u32 hw = (u32)(m >> (lane & 32));
        E[w] = hw;
        int jw = w & 31;
        u32 rootw = rootbits[jw];
        bool rooti = (rootbits[i >> 5] >> (i & 31)) & 1;
        u32 selfm = ((i >> 5) == jw) ? (1u << (i & 31)) : 0u;
        dagbits[w] = rooti ? (hw & ~rootw & ~selfm) : 0u;
    }
}

// ---- AT: 1024x1024 bit transpose ----
__global__ void transpose_bits_kernel(const u32* __restrict__ E, u32* __restrict__ ET)
{
    int hw = (blockIdx.x * blockDim.x + threadIdx.x) >> 5;
    int l = threadIdx.x & 31;
    int R = hw >> 5, C = hw & 31;
    u32 x = E[(R * 32 + l) * NW + C];
    #pragma unroll
    for (int s = 16; s >= 1; s >>= 1) {
        u32 mlo = (s == 16) ? 0x0000FFFFu : (s == 8) ? 0x00FF00FFu :
                  (s == 4) ? 0x0F0F0F0Fu : (s == 2) ? 0x33333333u : 0x55555555u;
        u32 y = __shfl_xor(x, s, 64);
        if ((l & s) == 0) x = (x & mlo) | ((y & mlo) << s);
        else              x = (x & ~mlo) | ((y & ~mlo) >> s);
    }
    ET[(C * 32 + l) * NW + R] = x;
}

// ---- B: sequential BFS, 512 threads, 1 barrier/iter common path ----
// Invariant: eff[cur] is ALWAYS the full effective anc row of current node i.
// Publisher folds (hit ? eff[cur]) at publish time -> no fix chains.
__global__ __launch_bounds__(NT) void dag_bfs_bits(
    const u32* __restrict__ E, const u32* __restrict__ ET,
    const u32* __restrict__ rootbits, u32* __restrict__ dagbits)
{
    extern __shared__ u32 smem[];
    u32* dag     = smem;                 // 32768 words (128 KiB)
    u32* eff     = dag + NN * NW;        // 3*32 words (triple buffer)
    u32* rootm   = eff + 3 * NW;         // 32
    u32* rootpre = rootm + 32;           // 32
    int* queue   = (int*)(rootpre + 32); // 1024
    u32* key     = (u32*)(queue + NN);   // 1024
    u64* mlo     = (u64*)(key + NN);     // 8
    u64* mhi     = mlo + 8;              // 8
    int* cnts    = (int*)(mhi + 8);      // 16 (double-buffered)

    const int tid  = threadIdx.x;
    const int lane = tid & 63;
    const int wid  = tid >> 6;
    const int myw  = tid >> 5;           // 0..15
    const u32 mybit = 1u << (tid & 31);

    {
        uint4 z = make_uint4(0, 0, 0, 0);
        uint4* d4 = (uint4*)dag;
        #pragma unroll
        for (int k = 0; k < 16; ++k) d4[tid + k * NT] = z;
    }
    if (tid < 32) rootm[tid] = rootbits[tid];
    __syncthreads();
    if (tid == 0) {
        int s = 0;
        #pragma unroll
        for (int w = 0; w < 32; ++w) { rootpre[w] = s; s += __popc(rootm[w]); }
    }

    bool root_lo = (rootm[tid >> 5] >> (tid & 31)) & 1;
    bool root_hi = (rootm[16 + (tid >> 5)] >> (tid & 31)) & 1;
    bool nr_lo = !root_lo, nr_hi = !root_hi;

    uint4 ancL[8], ancH[8];
    int fwL = -1, fwH = -1; u32 fwordL = 0, fwordH = 0;
    const uint4* rm4 = (const uint4*)rootm;
    {
        const uint4* ET4 = (const uint4*)ET + (size_t)tid * 8;
        #pragma unroll
        for (int k = 0; k < 8; ++k) {
            uint4 e = ET4[k], r = rm4[k];
            u32 a0 = nr_lo ? (e.x & r.x) : 0u;
            u32 a1 = nr_lo ? (e.y & r.y) : 0u;
            u32 a2 = nr_lo ? (e.z & r.z) : 0u;
            u32 a3 = nr_lo ? (e.w & r.w) : 0u;
            if (fwL < 0 && a0) { fwL = 4 * k + 0; fwordL = a0; }
            if (fwL < 0 && a1) { fwL = 4 * k + 1; fwordL = a1; }
            if (fwL < 0 && a2) { fwL = 4 * k + 2; fwordL = a2; }
            if (fwL < 0 && a3) { fwL = 4 * k + 3; fwordL = a3; }
            ancL[k].x = a0 | ((4 * k + 0 == myw) ? mybit : 0u);
            ancL[k].y = a1 | ((4 * k + 1 == myw) ? mybit : 0u);
            ancL[k].z = a2 | ((4 * k + 2 == myw) ? mybit : 0u);
            ancL[k].w = a3 | ((4 * k + 3 == myw) ? mybit : 0u);
        }
    }
    {
        const uint4* ET4 = (const uint4*)ET + (size_t)(tid + 512) * 8;
        #pragma unroll
        for (int k = 0; k < 8; ++k) {
            uint4 e = ET4[k], r = rm4[k];
            u32 a0 = nr_hi ? (e.x & r.x) : 0u;
            u32 a1 = nr_hi ? (e.y & r.y) : 0u;
            u32 a2 = nr_hi ? (e.z & r.z) : 0u;
            u32 a3 = nr_hi ? (e.w & r.w) : 0u;
            if (fwH < 0 && a0) { fwH = 4 * k + 0; fwordH = a0; }
            if (fwH < 0 && a1) { fwH = 4 * k + 1; fwordH = a1; }
            if (fwH < 0 && a2) { fwH = 4 * k + 2; fwordH = a2; }
            if (fwH < 0 && a3) { fwH = 4 * k + 3; fwordH = a3; }
            ancH[k].x = a0 | ((4 * k + 0 == 16 + myw) ? mybit : 0u);
            ancH[k].y = a1 | ((4 * k + 1 == 16 + myw) ? mybit : 0u);
            ancH[k].z = a2 | ((4 * k + 2 == 16 + myw) ? mybit : 0u);
            ancH[k].w = a3 | ((4 * k + 3 == 16 + myw) ? mybit : 0u);
        }
    }
    __syncthreads();

    u32 keyL = INF_KEY, keyH = INF_KEY;
    if (nr_lo && fwL >= 0) {
        int t0 = fwL * 32 + __ffs(fwordL) - 1;
        int rank = rootpre[t0 >> 5] + __popc(rootm[t0 >> 5] & ((1u << (t0 & 31)) - 1u));
        keyL = ((u32)rank << 10) | (u32)tid;
    }
    if (nr_hi && fwH >= 0) {
        int t0 = fwH * 32 + __ffs(fwordH) - 1;
        int rank = rootpre[t0 >> 5] + __popc(rootm[t0 >> 5] & ((1u << (t0 & 31)) - 1u));
        keyH = ((u32)rank << 10) | (u32)(tid + 512);
    }
    key[tid] = keyL; key[tid + 512] = keyH;
    __syncthreads();

    int posL = 0, posH = 0, tail = 0;
    {
        const uint4* key4 = (const uint4*)key;
        for (int q = 0; q < 256; ++q) {
            uint4 kk = key4[q];
            posL += (kk.x < keyL) + (kk.y < keyL) + (kk.z < keyL) + (kk.w < keyL);
            posH += (kk.x < keyH) + (kk.y < keyH) + (kk.z < keyH) + (kk.w < keyH);
            tail += (kk.x != INF_KEY) + (kk.y != INF_KEY) + (kk.z != INF_KEY) + (kk.w != INF_KEY);
        }
    }
    if (keyL != INF_KEY) queue[posL] = tid;
    if (keyH != INF_KEY) queue[posH] = tid + 512;
    __syncthreads();

    bool inqL = root_lo || (fwL >= 0);
    bool inqH = root_hi || (fwH >= 0);
    bool procL = false, procH = false, hitL = false, hitH = false;
    int head = 0, it = 0, cur = 0, nxt = 1, prv = 2;
    int i = -1; u32 ewL = 0, ewH = 0;
    if (tail > 0) {
        i = queue[0];
        bool owner = (i < 512) ? (tid == i) : (tid == i - 512);
        if (owner) {
            uint4* e4 = (uint4*)eff;
            if (i < 512) {
                #pragma unroll
                for (int k = 0; k < 8; ++k) e4[k] = ancL[k];
            } else {
                #pragma unroll
                for (int k = 0; k < 8; ++k) e4[k] = ancH[k];
            }
        }
        ewL = E[(size_t)i * NW + myw];
        ewH = E[(size_t)i * NW + 16 + myw];
    }
    __syncthreads();

    if (tail > 0) for (;;) {
        // ---- region A (pre-barrier) ----
        bool have_old = (head + 1 < tail);
        int qn = queue[have_old ? (head + 1) : head];
        u32 nwL = E[(size_t)qn * NW + myw];           // prefetch next E row
        u32 nwH = E[(size_t)qn * NW + 16 + myw];

        // deferred anc |= effective(prev) for last iteration's hits
        bool doL = hitL && !procL, doH = hitH && !procH;
        if (doL || doH) {
            const uint4* ep4 = (const uint4*)(eff + prv * NW);
            #pragma unroll
            for (int k = 0; k < 8; ++k) {
                uint4 s = ep4[k];
                if (doL) { ancL[k].x |= s.x; ancL[k].y |= s.y; ancL[k].z |= s.z; ancL[k].w |= s.w; }
                if (doH) { ancH[k].x |= s.x; ancH[k].y |= s.y; ancH[k].z |= s.z; ancH[k].w |= s.w; }
            }
        }
        if (i == tid) procL = true;
        if (i == tid + 512) procH = true;

        const u32* ec = eff + cur * NW;               // FULL effective row of i
        u32 aL = ec[myw];
        u32 aH = ec[16 + myw];
        hitL = ((ewL & mybit) != 0) && nr_lo && !(aL & mybit);
        hitH = ((ewH & mybit) != 0) && nr_hi && !(aH & mybit);

        u64 hmL = __ballot(hitL), hmH = __ballot(hitH);
        if (lane == 0) {
            *(u64*)(dag + (size_t)i * NW + 2 * wid)      = hmL;
            *(u64*)(dag + (size_t)i * NW + 16 + 2 * wid) = hmH;
        }
        bool nfL = hitL && !inqL; inqL |= nfL;
        bool nfH = hitH && !inqH; inqH |= nfH;
        u64 nmL = __ballot(nfL), nmH = __ballot(nfH);
        int off = (it & 1) * 8;
        if (lane == 0) {
            mlo[wid] = nmL; mhi[wid] = nmH;
            cnts[off + wid] = (int)(__popcll(nmL) + __popcll(nmH));
        }
        // publish qn's FULL effective row: regs | (hit-this-iter ? eff[cur])
        if (have_old) {
            if (qn == tid) {
                const uint4* ec4 = (const uint4*)ec;
                uint4* en = (uint4*)(eff + nxt * NW);
                #pragma unroll
                for (int k = 0; k < 8; ++k) {
                    uint4 b = ancL[k];
                    if (hitL) { uint4 s = ec4[k]; b.x |= s.x; b.y |= s.y; b.z |= s.z; b.w |= s.w; }
                    en[k] = b;
                }
            } else if (qn == tid + 512) {
                const uint4* ec4 = (const uint4*)ec;
                uint4* en = (uint4*)(eff + nxt * NW);
                #pragma unroll
                for (int k = 0; k < 8; ++k) {
                    uint4 b = ancH[k];
                    if (hitH) { uint4 s = ec4[k]; b.x |= s.x; b.y |= s.y; b.z |= s.z; b.w |= s.w; }
                    en[k] = b;
                }
            }
        }
        __syncthreads();

        // ---- post-barrier ----
        const int4* cp = (const int4*)(cnts + off);
        int4 c0 = cp[0], c1 = cp[1];
        int tot = c0.x + c0.y + c0.z + c0.w + c1.x + c1.y + c1.z + c1.w;
        it++; head++;
        if (tot == 0) {
            if (!have_old) break;
            i = qn; ewL = nwL; ewH = nwH;
            int t = prv; prv = cur; cur = nxt; nxt = t;
            continue;                                  // no LDS writes -> no 2nd barrier
        }
        // ---- rare path: enqueue new nodes (ascending j) ----
        int totlo = 0;
        #pragma unroll
        for (int w = 0; w < 8; ++w) totlo += (int)__popcll(mlo[w]);
        if (nfL) {
            int p = tail;
            #pragma unroll
            for (int w = 0; w < 8; ++w) if (w < wid) p += (int)__popcll(mlo[w]);
            p += (int)__popcll(nmL & ((1ULL << lane) - 1ULL));
            queue[p] = tid;
        }
        if (nfH) {
            int p = tail + totlo;
            #pragma unroll
            for (int w = 0; w < 8; ++w) if (w < wid) p += (int)__popcll(mhi[w]);
            p += (int)__popcll(nmH & ((1ULL << lane) - 1ULL));
            queue[p] = tid + 512;
        }
        tail += tot;
        if (have_old) {
            i = qn; ewL = nwL; ewH = nwH;
        } else {
            int fn = -1;
            #pragma unroll
            for (int w = 0; w < 8; ++w) if (fn < 0 && mlo[w]) fn = w * 64 + __ffsll((long long)mlo[w]) - 1;
            #pragma unroll
            for (int w = 0; w < 8; ++w) if (fn < 0 && mhi[w]) fn = 512 + w * 64 + __ffsll((long long)mhi[w]) - 1;
            i = fn;
            if (tid < 8) {                              // eff[nxt] = eff[cur] | {fn}
                uint4 b = ((const uint4*)(eff + cur * NW))[tid];
                if ((fn >> 7) == tid) {
                    u32 nb = 1u << (fn & 31);
                    int c = (fn >> 5) & 3;
                    if (c == 0) b.x |= nb; else if (c == 1) b.y |= nb;
                    else if (c == 2) b.z |= nb; else b.w |= nb;
                }
                ((uint4*)(eff + nxt * NW))[tid] = b;
            }
            ewL = E[(size_t)i * NW + myw];
            ewH = E[(size_t)i * NW + 16 + myw];
        }
        { int t = prv; prv = cur; cur = nxt; nxt = t; }
        __syncthreads();                               // queue/eff visible
    }

    // ---- flush non-root rows ----
    __syncthreads();
    const uint4* d4 = (const uint4*)dag;
    uint4* g4 = (uint4*)dagbits;
    #pragma unroll
    for (int k = 0; k < 16; ++k) {
        int q = tid + k * NT;
        int r = q >> 3;
        bool rt = (rootm[r >> 5] >> (r & 31)) & 1;
        if (!rt) g4[q] = d4[q];
    }
}

// ---- C: dag bits -> f32 output ----
__global__ void expand_kernel(const u32* __restrict__ dagbits, float4* __restrict__ out)
{
    int idx = blockIdx.x * blockDim.x + threadIdx.x;
    u32 w = dagbits[idx >> 3];
    int b = (idx & 7) * 4;
    float4 o;
    o.x = (w >> (b + 0)) & 1 ? 1.0f : 0.0f;
    o.y = (w >> (b + 1)) & 1 ? 1.0f : 0.0f;
    o.z = (w >> (b + 2)) & 1 ? 1.0f : 0.0f;
    o.w = (w >> (b + 3)) & 1 ? 1.0f : 0.0f;
    out[idx] = o;
}

extern "C" void kernel_launch(void* const* d_in, const int* in_sizes, int n_in,
                              void* d_out, int out_size, void* d_ws, size_t ws_size,
                              hipStream_t stream) {
    const float* root_probs = (const float*)d_in[0];
    const float* edge_probs = (const float*)d_in[1];
    const float* g_roots    = (const float*)d_in[2];
    const float* g_edges    = (const float*)d_in[3];

    u32* E        = (u32*)d_ws;
    u32* ET       = E + NN * NW;
    u32* dagbits  = ET + NN * NW;
    u32* rootbits = dagbits + NN * NW;

    root_bits_kernel<<<1, NN, 0, stream>>>(root_probs, g_roots, rootbits);
    edge_bits_kernel<<<NN * NN / 256, 256, 0, stream>>>(edge_probs, g_edges, rootbits, E, dagbits);
    transpose_bits_kernel<<<128, 256, 0, stream>>>(E, ET);

    size_t lds = (size_t)NN * NW * 4 + 3 * NW * 4 + 64 * 4 + NN * 4 + NN * 4
               + 16 * 8 + 16 * 4 + 64;
    hipFuncSetAttribute((const void*)dag_bfs_bits,
                        hipFuncAttributeMaxDynamicSharedMemorySize, (int)lds);
    dag_bfs_bits<<<1, NT, lds, stream>>>(E, ET, rootbits, dagbits);

    expand_kernel<<<NN * NN / 4 / 256, 256, 0, stream>>>(dagbits, (float4*)d_out);
}

// Round 7
// 627.313 us; speedup vs baseline: 1.2112x; 1.2112x over previous
//
#include <hip/hip_runtime.h>

#define NN 1024
#define NW 32
#define INF_KEY 0x7FFFFFFFu

typedef unsigned int u32;
typedef unsigned long long u64;

// ---- A0: root hard bits ----
__global__ __launch_bounds__(1024) void root_bits_kernel(
    const float* __restrict__ rp, const float* __restrict__ gr, u32* __restrict__ rootbits)
{
    int tid = threadIdx.x;
    float p = rp[tid];
    float2 g = reinterpret_cast<const float2*>(gr)[tid];
    bool root = (p + g.x) > ((1.0f - p) + g.y);
    u64 m = __ballot(root);
    if ((tid & 31) == 0) rootbits[tid >> 5] = (u32)(m >> (tid & 32));
}

// ---- A1: edge hard bits + root dag rows written directly ----
__global__ void edge_bits_kernel(const float* __restrict__ ep, const float* __restrict__ ge,
                                 const u32* __restrict__ rootbits,
                                 u32* __restrict__ E, u32* __restrict__ dagbits)
{
    int idx = blockIdx.x * blockDim.x + threadIdx.x;
    int i = idx >> 10;
    float p = ep[idx];
    float2 g = reinterpret_cast<const float2*>(ge)[idx];
    bool hard = (p + g.x) > ((1.0f - p) + g.y);
    u64 m = __ballot(hard);
    int lane = threadIdx.x & 63;
    if ((lane & 31) == 0) {
        int w = idx >> 5;
        u32 hw = (u32)(m >> (lane & 32));
        E[w] = hw;
        int jw = w & 31;
        u32 rootw = rootbits[jw];
        bool rooti = (rootbits[i >> 5] >> (i & 31)) & 1;
        u32 selfm = ((i >> 5) == jw) ? (1u << (i & 31)) : 0u;
        dagbits[w] = rooti ? (hw & ~rootw & ~selfm) : 0u;
    }
}

// ---- AT: 1024x1024 bit transpose ----
__global__ void transpose_bits_kernel(const u32* __restrict__ E, u32* __restrict__ ET)
{
    int hw = (blockIdx.x * blockDim.x + threadIdx.x) >> 5;
    int l = threadIdx.x & 31;
    int R = hw >> 5, C = hw & 31;
    u32 x = E[(R * 32 + l) * NW + C];
    #pragma unroll
    for (int s = 16; s >= 1; s >>= 1) {
        u32 mlo = (s == 16) ? 0x0000FFFFu : (s == 8) ? 0x00FF00FFu :
                  (s == 4) ? 0x0F0F0F0Fu : (s == 2) ? 0x33333333u : 0x55555555u;
        u32 y = __shfl_xor(x, s, 64);
        if ((l & s) == 0) x = (x & mlo) | ((y & mlo) << s);
        else              x = (x & ~mlo) | ((y & ~mlo) >> s);
    }
    ET[(C * 32 + l) * NW + R] = x;
}

// ---- B: sequential BFS; E in LDS; dag rows overwrite E rows; 3-deep pub pipeline ----
__global__ __launch_bounds__(1024) void dag_bfs(
    const u32* __restrict__ Eg, const u32* __restrict__ ET,
    const u32* __restrict__ rootbits, u32* __restrict__ dagbits)
{
    extern __shared__ u32 smem[];
    u32* Elds    = smem;                    // 32768 words (128K); becomes dag for processed rows
    u32* pub3    = Elds + NN * NW;          // 3*32
    u32* eff3    = pub3 + 96;               // 3*32
    u64* mask3   = (u64*)(eff3 + 96);       // 3*16 u64
    u64* prow    = mask3 + 48;              // 16 u64
    u32* rootm   = (u32*)(prow + 16);       // 32
    u32* rootpre = rootm + 32;              // 32
    u32* flagAB  = rootpre + 32;            // 2
    u32* cnt16   = flagAB + 2;              // 16
    int* queue   = (int*)(cnt16 + 16);      // 1024
    u32* key     = (u32*)(queue + NN);      // 1024

    const int tid  = threadIdx.x;
    const int lane = tid & 63;
    const int wid  = tid >> 6;
    const int myw  = tid >> 5;
    const int jbit = tid & 31;
    const u32 mybit = 1u << jbit;

    // E -> LDS
    {
        const uint4* Egl = (const uint4*)Eg;
        uint4* El4 = (uint4*)Elds;
        #pragma unroll
        for (int k = 0; k < 8; ++k) El4[tid + k * 1024] = Egl[tid + k * 1024];
    }
    if (tid < 32) rootm[tid] = rootbits[tid];
    if (tid < 48) mask3[tid] = 0ull;
    if (tid < 96) eff3[tid] = 0u;
    if (tid < 2)  flagAB[tid] = 0u;
    __syncthreads();

    if (tid == 0) {
        u32 s = 0;
        #pragma unroll
        for (int w = 0; w < 32; ++w) { rootpre[w] = s; s += __popc(rootm[w]); }
    }
    bool root = (rootm[tid >> 5] >> (tid & 31)) & 1;
    bool nonroot = !root;

    // anc[tid] = {tid} U {roots hitting tid}
    uint4 anc[8];
    int fw = -1; u32 fword = 0;
    {
        const uint4* ET4 = (const uint4*)ET + (size_t)tid * 8;
        const uint4* rm4 = (const uint4*)rootm;
        #pragma unroll
        for (int k = 0; k < 8; ++k) {
            uint4 e = ET4[k], r = rm4[k];
            u32 a0 = nonroot ? (e.x & r.x) : 0u;
            u32 a1 = nonroot ? (e.y & r.y) : 0u;
            u32 a2 = nonroot ? (e.z & r.z) : 0u;
            u32 a3 = nonroot ? (e.w & r.w) : 0u;
            if (fw < 0 && a0) { fw = 4 * k + 0; fword = a0; }
            if (fw < 0 && a1) { fw = 4 * k + 1; fword = a1; }
            if (fw < 0 && a2) { fw = 4 * k + 2; fword = a2; }
            if (fw < 0 && a3) { fw = 4 * k + 3; fword = a3; }
            anc[k].x = a0 | ((4 * k + 0 == myw) ? mybit : 0u);
            anc[k].y = a1 | ((4 * k + 1 == myw) ? mybit : 0u);
            anc[k].z = a2 | ((4 * k + 2 == myw) ? mybit : 0u);
            anc[k].w = a3 | ((4 * k + 3 == myw) ? mybit : 0u);
        }
    }
    __syncthreads();                 // rootpre ready

    // level-1 queue = nonroots sorted by (rank of first hitting root, tid)
    u32 mykey = INF_KEY;
    if (nonroot && fw >= 0) {
        int t0 = fw * 32 + __ffs(fword) - 1;
        int rank = (int)rootpre[t0 >> 5] + __popc(rootm[t0 >> 5] & ((1u << (t0 & 31)) - 1u));
        mykey = ((u32)rank << 10) | (u32)tid;
    }
    key[tid] = mykey;
    __syncthreads();
    int pos = 0, tail = 0;
    {
        const uint4* key4 = (const uint4*)key;
        for (int q = 0; q < 256; ++q) {
            uint4 kk = key4[q];
            pos  += (kk.x < mykey) + (kk.y < mykey) + (kk.z < mykey) + (kk.w < mykey);
            tail += (kk.x != INF_KEY) + (kk.y != INF_KEY) + (kk.z != INF_KEY) + (kk.w != INF_KEY);
        }
    }
    if (mykey != INF_KEY) queue[pos] = tid;
    __syncthreads();

    bool inq = root || (fw >= 0);
    bool proc = false, hit_prev = false, nf_prev = false;
    bool need_boot = true;
    int head = 0, s = 0, p0 = 0, p1 = 1, p2 = 2;
    int i = -1, qn = -1, wb_row = -1;
    u32 ew = 0, pubw = 0, effw2 = 0;
    u64 wb_mask = 0;

    for (;;) {
        // ---- flag check for phase s-1's discoveries ----
        u32 af = flagAB[(s + 1) & 1];
        if (af) {
            u64 nm2 = __ballot(nf_prev);
            if (lane == 0) cnt16[wid] = (u32)__popcll(nm2);
            __syncthreads();
            int off = 0, tot = 0;
            #pragma unroll
            for (int w = 0; w < 16; ++w) { int c = (int)cnt16[w]; if (w < wid) off += c; tot += c; }
            if (nf_prev) {
                int ppos = tail + off + (int)__popcll(nm2 & ((1ULL << lane) - 1ULL));
                queue[ppos] = tid;
            }
            tail += tot;
            if (tid == 0) flagAB[(s + 1) & 1] = 0u;
            nf_prev = false;
            __syncthreads();
            need_boot = true;
        }
        if (need_boot) {
            if (head >= tail) break;
            i = queue[head];
            qn = (head + 1 < tail) ? queue[head + 1] : -1;
            if (tid == i) {
                #pragma unroll
                for (int k = 0; k < 8; ++k) ((uint4*)(pub3 + p0 * 32))[k] = anc[k];
            }
            if (qn >= 0 && tid == qn) {
                #pragma unroll
                for (int k = 0; k < 8; ++k) ((uint4*)(pub3 + p1 * 32))[k] = anc[k];
            }
            __syncthreads();
            pubw  = pub3[p0 * 32 + myw];
            ew    = Elds[i * NW + myw];
            effw2 = eff3[p1 * 32 + myw];
            need_boot = false;
        } else if (head >= tail) break;

        // ---- phase s body ----
        u64 mA = mask3[p2 * 16 + (i >> 6)];          // hit(s-1, i)
        u64 mB = mask3[p1 * 16 + (i >> 6)];          // hit(s-2, i)
        u32 e1 = eff3[p2 * 32 + myw];                // eff row of i_{s-1}, own word
        if (wb_row >= 0 && lane == 0)                // deferred dag writeback (row dead)
            *(u64*)(Elds + wb_row * NW + 2 * wid) = wb_mask;
        int qn2   = (head + 2 < tail) ? queue[head + 2] : -1;
        u32 ewn   = (qn >= 0) ? Elds[qn * NW + myw] : 0u;
        u32 pub_n = (qn >= 0) ? pub3[p1 * 32 + myw] : 0u;

        u32 b_a = (u32)(mA >> (i & 63)) & 1u;
        u32 b_b = (u32)(mB >> (i & 63)) & 1u;
        u32 myeffw = pubw | (b_a ? e1 : 0u) | (b_b ? effw2 : 0u);
        bool hit = (((ew >> jbit) & 1u) != 0u) && nonroot && (((myeffw >> jbit) & 1u) == 0u);
        u64 hm = __ballot(hit);
        bool nf = hit && !inq;
        inq = inq || hit;
        u64 nm = __ballot(nf);
        if (lane == 0) {
            mask3[p0 * 16 + wid] = hm;
            if (nm) flagAB[s & 1] = 1u;
        }
        if ((tid & 31) == 0) eff3[p0 * 32 + myw] = myeffw;
        proc = proc || (tid == i);
        if (hit_prev && !proc) {                     // deferred fold of eff_{s-1}
            const uint4* ef = (const uint4*)(eff3 + p2 * 32);
            #pragma unroll
            for (int k = 0; k < 8; ++k) {
                uint4 v = ef[k];
                anc[k].x |= v.x; anc[k].y |= v.y; anc[k].z |= v.z; anc[k].w |= v.w;
            }
        }
        if (qn2 >= 0 && tid == qn2) {                // publish PUB(i_{s+2}) (post-fold)
            #pragma unroll
            for (int k = 0; k < 8; ++k) ((uint4*)(pub3 + p2 * 32))[k] = anc[k];
        }
        __syncthreads();

        // ---- transition ----
        wb_row = i; wb_mask = hm;
        i = qn; ew = ewn; pubw = pub_n; effw2 = e1;
        hit_prev = hit; nf_prev = nf;
        qn = qn2;
        int tp = p0; p0 = p1; p1 = p2; p2 = tp;
        s++; head++;
    }

    // final dag writeback + processed bitmap + flush
    if (wb_row >= 0 && lane == 0)
        *(u64*)(Elds + wb_row * NW + 2 * wid) = wb_mask;
    {
        u64 pm = __ballot(proc);
        if (lane == 0) prow[wid] = pm;
    }
    __syncthreads();
    {
        const uint4* El4 = (const uint4*)Elds;
        uint4* g4 = (uint4*)dagbits;
        #pragma unroll
        for (int k = 0; k < 8; ++k) {
            int q = tid + k * 1024;          // uint4 index; row = q>>3
            int r = q >> 3;
            bool rt = (rootm[r >> 5] >> (r & 31)) & 1;
            if (!rt) {
                bool pr = (prow[r >> 6] >> (r & 63)) & 1;
                uint4 v = pr ? El4[q] : make_uint4(0u, 0u, 0u, 0u);
                g4[q] = v;
            }
        }
    }
}

// ---- C: dag bits -> f32 output ----
__global__ void expand_kernel(const u32* __restrict__ dagbits, float4* __restrict__ out)
{
    int idx = blockIdx.x * blockDim.x + threadIdx.x;
    u32 w = dagbits[idx >> 3];
    int b = (idx & 7) * 4;
    float4 o;
    o.x = (w >> (b + 0)) & 1 ? 1.0f : 0.0f;
    o.y = (w >> (b + 1)) & 1 ? 1.0f : 0.0f;
    o.z = (w >> (b + 2)) & 1 ? 1.0f : 0.0f;
    o.w = (w >> (b + 3)) & 1 ? 1.0f : 0.0f;
    out[idx] = o;
}

extern "C" void kernel_launch(void* const* d_in, const int* in_sizes, int n_in,
                              void* d_out, int out_size, void* d_ws, size_t ws_size,
                              hipStream_t stream) {
    const float* root_probs = (const float*)d_in[0];
    const float* edge_probs = (const float*)d_in[1];
    const float* g_roots    = (const float*)d_in[2];
    const float* g_edges    = (const float*)d_in[3];

    u32* E        = (u32*)d_ws;
    u32* ET       = E + NN * NW;
    u32* dagbits  = ET + NN * NW;
    u32* rootbits = dagbits + NN * NW;

    root_bits_kernel<<<1, NN, 0, stream>>>(root_probs, g_roots, rootbits);
    edge_bits_kernel<<<NN * NN / 256, 256, 0, stream>>>(edge_probs, g_edges, rootbits, E, dagbits);
    transpose_bits_kernel<<<128, 256, 0, stream>>>(E, ET);

    size_t lds = (size_t)NN * NW * 4   // Elds
               + 96 * 4 + 96 * 4       // pub3, eff3
               + 48 * 8 + 16 * 8       // mask3, prow
               + 32 * 4 + 32 * 4       // rootm, rootpre
               + 2 * 4 + 16 * 4        // flagAB, cnt16
               + NN * 4 + NN * 4;      // queue, key
    hipFuncSetAttribute((const void*)dag_bfs,
                        hipFuncAttributeMaxDynamicSharedMemorySize, (int)lds);
    dag_bfs<<<1, NN, lds, stream>>>(E, ET, rootbits, dagbits);

    expand_kernel<<<NN * NN / 4 / 256, 256, 0, stream>>>(dagbits, (float4*)d_out);
}